// Round 12
// baseline (1478.011 us; speedup 1.0000x reference)
//
#include <hip/hip_runtime.h>

#define HW 196
#define WIDTH 14
#define T_STEPS 32
#define KC 64      // centers / GRU channels
#define DD 512     // reduced dim
#define CIN 1024
#define NFR 256    // B*T
#define NB 8       // videos
#define NCOL (NFR * HW)   // 50176

using f16x8 = __attribute__((ext_vector_type(8))) _Float16;
using f16x4 = __attribute__((ext_vector_type(4))) _Float16;
using f32x4 = __attribute__((ext_vector_type(4))) float;

__device__ __forceinline__ void gload_lds16(const void* g, void* l) {
  __builtin_amdgcn_global_load_lds(
      (const __attribute__((address_space(1))) void*)g,
      (__attribute__((address_space(3))) void*)l, 16, 0, 0);
}

// fast sigmoid / tanh: v_exp_f32 + v_rcp_f32; exact saturation at +-inf.
// (validated rounds 7-10: absmax unchanged at 6.1e-5)
__device__ __forceinline__ float sigf(float x) {
  return __builtin_amdgcn_rcpf(1.0f + __expf(-x));
}
__device__ __forceinline__ float tanhfast(float x) {
  float e = __expf(2.0f * x);
  return 1.0f - 2.0f * __builtin_amdgcn_rcpf(e + 1.0f);
}

// ---------------------------------------------------------------------------
// f32 -> f16 elementwise convert (weights). nelem multiple of 4.
// ---------------------------------------------------------------------------
__global__ __launch_bounds__(256)
void cvt_f16(const float* __restrict__ src, _Float16* __restrict__ dst, int nelem) {
  int i = (blockIdx.x * 256 + threadIdx.x) * 4;
  if (i < nelem) {
    float4 v = *reinterpret_cast<const float4*>(src + i);
    f16x4 o;
    o[0] = (_Float16)v.x; o[1] = (_Float16)v.y;
    o[2] = (_Float16)v.z; o[3] = (_Float16)v.w;
    *reinterpret_cast<f16x4*>(dst + i) = o;
  }
}

// ---------------------------------------------------------------------------
// Transpose-convert x: (n, c, p) f32 -> xh[(n*196+p)][c] f16.
// ---------------------------------------------------------------------------
__global__ __launch_bounds__(256)
void transpose_x(const float* __restrict__ x, _Float16* __restrict__ xh) {
  __shared__ float tile[64][197];
  const int tid = threadIdx.x;
  const int w = tid >> 6, lane = tid & 63;
  const int n = blockIdx.y;
  const int c0 = blockIdx.x * 64;
  const float* src = x + ((size_t)n * CIN + c0) * HW;
  for (int rr = 0; rr < 16; ++rr) {
    int c = w * 16 + rr;
    if (lane < 49) {
      float4 v = *reinterpret_cast<const float4*>(src + (size_t)c * HW + lane * 4);
      tile[c][lane * 4 + 0] = v.x; tile[c][lane * 4 + 1] = v.y;
      tile[c][lane * 4 + 2] = v.z; tile[c][lane * 4 + 3] = v.w;
    }
  }
  __syncthreads();
  _Float16* dst = xh + (size_t)n * HW * CIN + c0;
  for (int pp = 0; pp < 49; ++pp) {
    int p = w + pp * 4;
    dst[(size_t)p * CIN + lane] = (_Float16)tile[lane][p];
  }
}

// ---------------------------------------------------------------------------
// f16 MFMA GEMM (validated round 4/5): out[m][col] = bias[m]+sum_k A[m][k]*B[col][k]
// WT: write outT[col][M] f16 (LDS-transposed) -- stage A.
// !WT: write outC[col][M] f32 (float4, k-contiguous) -- stage B.
// ---------------------------------------------------------------------------
template<int BM, int NMT, bool WT>
__global__ __launch_bounds__(256)
void gemm16(const _Float16* __restrict__ A, const _Float16* __restrict__ Bmat,
            const float* __restrict__ bias, float* __restrict__ outC,
            _Float16* __restrict__ outT, int M, int K) {
  constexpr int MF = BM / 32;
  union Smem {
    struct { _Float16 a[BM * 64]; _Float16 b[128 * 64]; } s;
    _Float16 t[WT ? 128 * 132 : 1];
  };
  __shared__ Smem u;

  const int tid = threadIdx.x;
  const int lane = tid & 63;
  const int w = tid >> 6;
  const int wm = w >> 1, wn = w & 1;
  const int l16 = lane & 15, lhi = lane >> 4;
  const int srow = lane >> 3, sslot = lane & 7;
  const int swz = (sslot ^ srow) << 4;
  const int mt = blockIdx.x & (NMT - 1);
  const int ct = blockIdx.x / NMT;
  const int m0 = mt * BM;
  const int col0 = ct * 128;

  f32x4 acc[MF][4];
  #pragma unroll
  for (int i = 0; i < MF; ++i)
    #pragma unroll
    for (int f = 0; f < 4; ++f) acc[i][f] = {0.f, 0.f, 0.f, 0.f};

  for (int k0 = 0; k0 < K; k0 += 64) {
    #pragma unroll
    for (int s = 0; s < BM / 32; ++s) {
      int r = w * (BM / 4) + s * 8;
      gload_lds16((const char*)(A + (size_t)(m0 + r + srow) * K + k0) + swz,
                  (char*)u.s.a + r * 128);
    }
    #pragma unroll
    for (int s = 0; s < 4; ++s) {
      int r = w * 32 + s * 8;
      gload_lds16((const char*)(Bmat + (size_t)(col0 + r + srow) * K + k0) + swz,
                  (char*)u.s.b + r * 128);
    }
    __syncthreads();
    #pragma unroll
    for (int kk = 0; kk < 2; ++kk) {
      f16x8 af[MF];
      #pragma unroll
      for (int i = 0; i < MF; ++i) {
        int row = wm * (MF * 16) + i * 16 + l16;
        af[i] = *reinterpret_cast<const f16x8*>(
            (const char*)u.s.a + row * 128 + ((kk * 64 + lhi * 16) ^ ((row & 7) << 4)));
      }
      #pragma unroll
      for (int f = 0; f < 4; ++f) {
        int row = wn * 64 + f * 16 + l16;
        f16x8 bf = *reinterpret_cast<const f16x8*>(
            (const char*)u.s.b + row * 128 + ((kk * 64 + lhi * 16) ^ ((row & 7) << 4)));
        #pragma unroll
        for (int i = 0; i < MF; ++i)
          acc[i][f] = __builtin_amdgcn_mfma_f32_16x16x32_f16(af[i], bf, acc[i][f], 0, 0, 0);
      }
    }
    __syncthreads();
  }

  if constexpr (!WT) {
    #pragma unroll
    for (int i = 0; i < MF; ++i) {
      int m = m0 + wm * (MF * 16) + i * 16 + lhi * 4;
      float b0 = bias[m], b1 = bias[m + 1], b2 = bias[m + 2], b3 = bias[m + 3];
      #pragma unroll
      for (int f = 0; f < 4; ++f) {
        int col = col0 + wn * 64 + f * 16 + l16;
        float4 o = {acc[i][f][0] + b0, acc[i][f][1] + b1,
                    acc[i][f][2] + b2, acc[i][f][3] + b3};
        *reinterpret_cast<float4*>(outC + (size_t)col * M + m) = o;
      }
    }
  } else {
    #pragma unroll
    for (int i = 0; i < MF; ++i) {
      int ml = wm * (MF * 16) + i * 16 + lhi * 4;
      int m = m0 + ml;
      float b0 = bias[m], b1 = bias[m + 1], b2 = bias[m + 2], b3 = bias[m + 3];
      #pragma unroll
      for (int f = 0; f < 4; ++f) {
        int cl = wn * 64 + f * 16 + l16;
        f16x4 v;
        v[0] = (_Float16)(acc[i][f][0] + b0);
        v[1] = (_Float16)(acc[i][f][1] + b1);
        v[2] = (_Float16)(acc[i][f][2] + b2);
        v[3] = (_Float16)(acc[i][f][3] + b3);
        *reinterpret_cast<f16x4*>((char*)u.t + cl * 264 + ml * 2) = v;
      }
    }
    __syncthreads();
    #pragma unroll
    for (int pass = 0; pass < 16; ++pass) {
      int row = (tid >> 5) + pass * 8;
      int coff = (tid & 31) * 4;
      f16x4 v = *reinterpret_cast<const f16x4*>((const char*)u.t + row * 264 + coff * 2);
      *reinterpret_cast<f16x4*>(outT + (size_t)(col0 + row) * M + m0 + coff) = v;
    }
  }
}

// ---------------------------------------------------------------------------
// Pre-format U weights into MFMA A-fragments (validated round 3).
// ---------------------------------------------------------------------------
__global__ __launch_bounds__(64)
void format_u(const float* __restrict__ Uz, const float* __restrict__ Ur,
              const float* __restrict__ Uh, _Float16* __restrict__ ufmt) {
  const int f = blockIdx.x;        // 0..215
  const int lane = threadIdx.x;
  const int l16 = lane & 15;
  const float* U;
  int ch, kt;
  if (f < 144) {
    int pair = f / 36, rem = f - pair * 36;
    int mi = rem / 18; kt = rem - mi * 18;
    U = (pair < 2) ? Uz : Ur;
    ch = (pair & 1) * 32 + mi * 16 + l16;
  } else {
    int g = f - 144;
    int pair = g / 36, rem = g - pair * 36;
    int mi = rem / 18; kt = rem - mi * 18;
    U = Uh;
    ch = pair * 32 + mi * 16 + l16;
  }
  const int tap = kt >> 1;
  const int k0 = (kt & 1) * 32 + (lane >> 4) * 8;
  f16x8 v;
  #pragma unroll
  for (int j = 0; j < 8; ++j)
    v[j] = (_Float16)U[(size_t)ch * 576 + (k0 + j) * 9 + tap];
  *reinterpret_cast<f16x8*>(ufmt + (size_t)f * 512 + lane * 8) = v;
}

// ---------------------------------------------------------------------------
// GRU v7 = round-10 proven kernel (512 thr, LDS state, VGPR 128 no-spill,
// fast activations, precomputed swizzle bases -- 443 us) with wave
// re-partition to halve LDS bf duplication:
//   wave = (mig = w&1 : 32-ch group, q = w>>1 : tile quarter).
//   Phase1: ONE bf read feeds 4 MFMA (z-mi0, z-mi1, r-mi0, r-mi1).
//   Phase2: one bf -> 2 MFMA (h-mi0, h-mi1).
// bf ds_read_b128 per CU per step: 1872 -> 936. af (4 frags/kt) streams from
// L2-resident ufmt; acc = 16 VGPR; math identical to round 10.
// ---------------------------------------------------------------------------
__global__ __launch_bounds__(512, 2)
void gru_mfma8(const float* __restrict__ wxbc, const _Float16* __restrict__ ufmt,
               _Float16* __restrict__ a_f, _Float16* __restrict__ a_b) {
  __shared__ __align__(16) _Float16 hpad[256 * 64];   // 32KB padded h (swizzled)
  __shared__ __align__(16) _Float16 rhpad[256 * 64];  // 32KB padded r*h
  __shared__ __align__(16) _Float16 zbuf[208 * 64];   // 26.6KB z (swizzled)
  __shared__ __align__(16) float h32[HW * 68];        // 52KB fp32 h, padded rows

  const int tid = threadIdx.x;
  const int lane = tid & 63;
  const int w = tid >> 6;            // wave 0..7
  const int l16 = lane & 15, lhi = lane >> 4;
  const int chain = blockIdx.x;
  const int b = chain >> 1, dir = chain & 1;
  const int mig = w & 1;             // 32-ch group
  const int q = w >> 1;              // tile quarter 0..3
  const int chA = mig * 32 + lhi * 4;       // mi0 channel base (lane quad)
  const int chB = chA + 16;                 // mi1 channel base
  const int chlo = lhi * 16, chhi = 64 + lhi * 16;
  const int fz0 = mig * 36;          // frag base: z mi0 @ fz0, mi1 @ fz0+18,
                                     // r @ +72/+90, h @ 144+fz0 / +18

  for (int i = tid; i < 256 * 64; i += 512) { hpad[i] = (_Float16)0.f; rhpad[i] = (_Float16)0.f; }
  for (int i = tid; i < HW * 68; i += 512) h32[i] = 0.0f;
  __syncthreads();

  _Float16* adest = dir ? a_b : a_f;
  const char* hpadB = reinterpret_cast<const char*>(hpad);
  const char* rhpadB = reinterpret_cast<const char*>(rhpad);
  const _Float16* uf = ufmt + (size_t)lane * 8;

  for (int t = 0; t < T_STEPS; ++t) {
    const int tw = dir ? (T_STEPS - 1 - t) : t;
    const float* wtc = wxbc + (size_t)(b * T_STEPS + tw) * HW * KC;

    // ================= phase 1: z -> zbuf, r*h -> rhpad ====================
    for (int it = 0; it < 4; ++it) {
      const int nt = q + 4 * it;
      if (nt > 12) break;
      const int p = nt * 16 + l16;
      const bool act = p < HW;
      const int pc = act ? p : (HW - 1);
      const int py = pc / 14, px_ = pc - py * 14;
      const int base0 = py * 16 + px_;
      const int tb = base0 * 128;
      const int rb0 = tb +       (chlo ^ ((px_ & 7) << 4));
      const int rb1 = tb + 128 + (chlo ^ (((px_ + 1) & 7) << 4));
      const int rb2 = tb + 256 + (chlo ^ (((px_ + 2) & 7) << 4));
      const int rb3 = tb +       (chhi ^ ((px_ & 7) << 4));
      const int rb4 = tb + 128 + (chhi ^ (((px_ + 1) & 7) << 4));
      const int rb5 = tb + 256 + (chhi ^ (((px_ + 2) & 7) << 4));
      const float4 wtA4 = *reinterpret_cast<const float4*>(wtc + (size_t)pc * KC + chA);
      const float4 wtB4 = *reinterpret_cast<const float4*>(wtc + (size_t)pc * KC + chB);
      f32x4 az0 = {0.f, 0.f, 0.f, 0.f};
      f32x4 az1 = {0.f, 0.f, 0.f, 0.f};
      f32x4 ar0 = {0.f, 0.f, 0.f, 0.f};
      f32x4 ar1 = {0.f, 0.f, 0.f, 0.f};
      #pragma unroll
      for (int kt = 0; kt < 18; ++kt) {
        const int tap = kt >> 1, dy = tap / 3, dx = tap - dy * 3;
        const int base = (kt & 1) ? (dx == 0 ? rb3 : dx == 1 ? rb4 : rb5)
                                  : (dx == 0 ? rb0 : dx == 1 ? rb1 : rb2);
        const f16x8 bf = *reinterpret_cast<const f16x8*>(hpadB + base + dy * 2048);
        const f16x8 a0 = *reinterpret_cast<const f16x8*>(uf + (size_t)(fz0 + kt) * 512);
        const f16x8 a1 = *reinterpret_cast<const f16x8*>(uf + (size_t)(fz0 + 18 + kt) * 512);
        const f16x8 a2 = *reinterpret_cast<const f16x8*>(uf + (size_t)(fz0 + 72 + kt) * 512);
        const f16x8 a3 = *reinterpret_cast<const f16x8*>(uf + (size_t)(fz0 + 90 + kt) * 512);
        az0 = __builtin_amdgcn_mfma_f32_16x16x32_f16(a0, bf, az0, 0, 0, 0);
        az1 = __builtin_amdgcn_mfma_f32_16x16x32_f16(a1, bf, az1, 0, 0, 0);
        ar0 = __builtin_amdgcn_mfma_f32_16x16x32_f16(a2, bf, ar0, 0, 0, 0);
        ar1 = __builtin_amdgcn_mfma_f32_16x16x32_f16(a3, bf, ar1, 0, 0, 0);
      }
      if (act) {
        const int ppw = base0 + 17;
        {
          const float wta[4] = {wtA4.x, wtA4.y, wtA4.z, wtA4.w};
          const float4 hv = *reinterpret_cast<const float4*>(&h32[pc * 68 + chA]);
          const float hva[4] = {hv.x, hv.y, hv.z, hv.w};
          f16x4 zw, rhw;
          #pragma unroll
          for (int jj = 0; jj < 4; ++jj) {
            float z = sigf(az0[jj] + wta[jj]);
            float r = sigf(ar0[jj] + wta[jj]);
            zw[jj] = (_Float16)z;
            rhw[jj] = (_Float16)(r * hva[jj]);
          }
          *reinterpret_cast<f16x4*>(reinterpret_cast<char*>(zbuf) +
              p * 128 + ((chA * 2) ^ ((p & 7) << 4))) = zw;
          *reinterpret_cast<f16x4*>(reinterpret_cast<char*>(rhpad) +
              ppw * 128 + ((chA * 2) ^ ((ppw & 7) << 4))) = rhw;
        }
        {
          const float wta[4] = {wtB4.x, wtB4.y, wtB4.z, wtB4.w};
          const float4 hv = *reinterpret_cast<const float4*>(&h32[pc * 68 + chB]);
          const float hva[4] = {hv.x, hv.y, hv.z, hv.w};
          f16x4 zw, rhw;
          #pragma unroll
          for (int jj = 0; jj < 4; ++jj) {
            float z = sigf(az1[jj] + wta[jj]);
            float r = sigf(ar1[jj] + wta[jj]);
            zw[jj] = (_Float16)z;
            rhw[jj] = (_Float16)(r * hva[jj]);
          }
          *reinterpret_cast<f16x4*>(reinterpret_cast<char*>(zbuf) +
              p * 128 + ((chB * 2) ^ ((p & 7) << 4))) = zw;
          *reinterpret_cast<f16x4*>(reinterpret_cast<char*>(rhpad) +
              ppw * 128 + ((chB * 2) ^ ((ppw & 7) << 4))) = rhw;
        }
      }
    }
    __syncthreads();

    // ================= phase 2: hh = tanh(wt + conv(rh,Uh)); update h ======
    {
      _Float16* ad = adest + (size_t)(b * T_STEPS + tw) * HW * KC;
      for (int it = 0; it < 4; ++it) {
        const int nt = q + 4 * it;
        if (nt > 12) break;
        const int p = nt * 16 + l16;
        const bool act = p < HW;
        const int pc = act ? p : (HW - 1);
        const int py = pc / 14, px_ = pc - py * 14;
        const int base0 = py * 16 + px_;
        const int tb = base0 * 128;
        const int rb0 = tb +       (chlo ^ ((px_ & 7) << 4));
        const int rb1 = tb + 128 + (chlo ^ (((px_ + 1) & 7) << 4));
        const int rb2 = tb + 256 + (chlo ^ (((px_ + 2) & 7) << 4));
        const int rb3 = tb +       (chhi ^ ((px_ & 7) << 4));
        const int rb4 = tb + 128 + (chhi ^ (((px_ + 1) & 7) << 4));
        const int rb5 = tb + 256 + (chhi ^ (((px_ + 2) & 7) << 4));
        const float4 wtA4 = *reinterpret_cast<const float4*>(wtc + (size_t)pc * KC + chA);
        const float4 wtB4 = *reinterpret_cast<const float4*>(wtc + (size_t)pc * KC + chB);
        f32x4 ah0 = {0.f, 0.f, 0.f, 0.f};
        f32x4 ah1 = {0.f, 0.f, 0.f, 0.f};
        #pragma unroll
        for (int kt = 0; kt < 18; ++kt) {
          const int tap = kt >> 1, dy = tap / 3, dx = tap - dy * 3;
          const int base = (kt & 1) ? (dx == 0 ? rb3 : dx == 1 ? rb4 : rb5)
                                    : (dx == 0 ? rb0 : dx == 1 ? rb1 : rb2);
          const f16x8 bf = *reinterpret_cast<const f16x8*>(rhpadB + base + dy * 2048);
          const f16x8 a0 = *reinterpret_cast<const f16x8*>(uf + (size_t)(144 + fz0 + kt) * 512);
          const f16x8 a1 = *reinterpret_cast<const f16x8*>(uf + (size_t)(144 + fz0 + 18 + kt) * 512);
          ah0 = __builtin_amdgcn_mfma_f32_16x16x32_f16(a0, bf, ah0, 0, 0, 0);
          ah1 = __builtin_amdgcn_mfma_f32_16x16x32_f16(a1, bf, ah1, 0, 0, 0);
        }
        if (act) {
          const int ppw = base0 + 17;
          {
            const float wta[4] = {wtA4.x, wtA4.y, wtA4.z, wtA4.w};
            const f16x4 zv = *reinterpret_cast<const f16x4*>(
                reinterpret_cast<const char*>(zbuf) + p * 128 + ((chA * 2) ^ ((p & 7) << 4)));
            const float4 hv = *reinterpret_cast<const float4*>(&h32[pc * 68 + chA]);
            const float hva[4] = {hv.x, hv.y, hv.z, hv.w};
            f16x4 hw;
            float hna[4];
            #pragma unroll
            for (int jj = 0; jj < 4; ++jj) {
              float hh = tanhfast(ah0[jj] + wta[jj]);
              float z = (float)zv[jj];
              float hn = hh + z * (hva[jj] - hh);
              hna[jj] = hn;
              hw[jj] = (_Float16)hn;
            }
            float4 hn4 = {hna[0], hna[1], hna[2], hna[3]};
            *reinterpret_cast<float4*>(&h32[pc * 68 + chA]) = hn4;
            *reinterpret_cast<f16x4*>(reinterpret_cast<char*>(hpad) +
                ppw * 128 + ((chA * 2) ^ ((ppw & 7) << 4))) = hw;
            *reinterpret_cast<f16x4*>(ad + (size_t)pc * KC + chA) = hw;
          }
          {
            const float wta[4] = {wtB4.x, wtB4.y, wtB4.z, wtB4.w};
            const f16x4 zv = *reinterpret_cast<const f16x4*>(
                reinterpret_cast<const char*>(zbuf) + p * 128 + ((chB * 2) ^ ((p & 7) << 4)));
            const float4 hv = *reinterpret_cast<const float4*>(&h32[pc * 68 + chB]);
            const float hva[4] = {hv.x, hv.y, hv.z, hv.w};
            f16x4 hw;
            float hna[4];
            #pragma unroll
            for (int jj = 0; jj < 4; ++jj) {
              float hh = tanhfast(ah1[jj] + wta[jj]);
              float z = (float)zv[jj];
              float hn = hh + z * (hva[jj] - hh);
              hna[jj] = hn;
              hw[jj] = (_Float16)hn;
            }
            float4 hn4 = {hna[0], hna[1], hna[2], hna[3]};
            *reinterpret_cast<float4*>(&h32[pc * 68 + chB]) = hn4;
            *reinterpret_cast<f16x4*>(reinterpret_cast<char*>(hpad) +
                ppw * 128 + ((chB * 2) ^ ((ppw & 7) << 4))) = hw;
            *reinterpret_cast<f16x4*>(ad + (size_t)pc * KC + chB) = hw;
          }
        }
      }
    }
    __syncthreads();
  }
}

// ---------------------------------------------------------------------------
// softmax over K=64 per pixel-row; logits = a_f + a_b (f16, [n][p][k]),
// output f32 [n][p][k].
// ---------------------------------------------------------------------------
__global__ __launch_bounds__(256)
void softmax_kernel(const _Float16* __restrict__ af, const _Float16* __restrict__ ab,
                    float* __restrict__ out) {
  size_t idx = (size_t)blockIdx.x * 256 + threadIdx.x;   // 0..50175
  const _Float16* cf = af + idx * KC;
  const _Float16* cb = ab + idx * KC;
  float* co = out + idx * KC;
  float v[KC];
  float mx = -3.4e38f;
  #pragma unroll
  for (int g = 0; g < 8; ++g) {
    f16x8 a = *reinterpret_cast<const f16x8*>(cf + g * 8);
    f16x8 bq = *reinterpret_cast<const f16x8*>(cb + g * 8);
    #pragma unroll
    for (int j = 0; j < 8; ++j) {
      float s = (float)a[j] + (float)bq[j];
      v[g * 8 + j] = s;
      mx = fmaxf(mx, s);
    }
  }
  float ssum = 0.0f;
  #pragma unroll
  for (int k = 0; k < KC; ++k) { v[k] = expf(v[k] - mx); ssum += v[k]; }
  float inv = 1.0f / ssum;
  #pragma unroll
  for (int g = 0; g < 16; ++g) {
    float4 o = {v[g * 4] * inv, v[g * 4 + 1] * inv, v[g * 4 + 2] * inv, v[g * 4 + 3] * inv};
    *reinterpret_cast<float4*>(co + g * 4) = o;
  }
}

// ---------------------------------------------------------------------------
// S[b][k] = sum over (t,p) of assign ([n][p][k] layout). grid (8 seg, 8 b).
// ---------------------------------------------------------------------------
__global__ __launch_bounds__(256)
void sreduce_kernel(const float* __restrict__ a, float* __restrict__ S) {
  __shared__ float red[4][64];
  const int seg = blockIdx.x, b = blockIdx.y, tid = threadIdx.x;
  const int k = tid & 63, rg = tid >> 6;
  const float* base = a + (size_t)b * T_STEPS * HW * KC;
  float sum = 0.0f;
  for (int rr = seg * 784 + rg; rr < (seg + 1) * 784; rr += 4)
    sum += base[(size_t)rr * KC + k];
  red[rg][k] = sum;
  __syncthreads();
  if (tid < 64) {
    float s = red[0][k] + red[1][k] + red[2][k] + red[3][k];
    atomicAdd(&S[b * KC + k], s);
  }
}

// ---------------------------------------------------------------------------
// VLAD GEMM partials; assign [n][p][k] f32, xrh [n*196+p][512] f16.
// ---------------------------------------------------------------------------
__global__ __launch_bounds__(256)
void vlad_gemm_kernel(const float* __restrict__ a, const _Float16* __restrict__ xrh,
                      float* __restrict__ Gpart) {
  __shared__ float sA[16][68];
  __shared__ float sX[16][68];
  const int tid = threadIdx.x;
  const int tx = tid & 15, ty = tid >> 4;
  const int d0 = blockIdx.x * 64;
  const int tc = blockIdx.y;
  const int b  = blockIdx.z;
  const int kk = tid & 63, pj = tid >> 6;
  float acc[4][4] = {};

  for (int tt = 0; tt < 8; ++tt) {
    int n = b * T_STEPS + tc * 8 + tt;
    const float* an = a + (size_t)n * HW * KC;
    const _Float16* xn = xrh + (size_t)n * HW * DD;
    for (int p0 = 0; p0 < HW; p0 += 16) {
      __syncthreads();
      #pragma unroll
      for (int j = 0; j < 4; ++j) {
        int pl = pj * 4 + j;
        int p = p0 + pl;
        sA[pl][kk] = (p < HW) ? an[(size_t)p * KC + kk] : 0.0f;
        sX[pl][kk] = (p < HW) ? (float)xn[(size_t)p * DD + d0 + kk] : 0.0f;
      }
      __syncthreads();
      #pragma unroll
      for (int pp = 0; pp < 16; ++pp) {
        float4 av = *reinterpret_cast<const float4*>(&sA[pp][ty * 4]);
        float4 xv = *reinterpret_cast<const float4*>(&sX[pp][tx * 4]);
        float aa[4] = {av.x, av.y, av.z, av.w};
        float xx[4] = {xv.x, xv.y, xv.z, xv.w};
        #pragma unroll
        for (int i = 0; i < 4; ++i)
          #pragma unroll
          for (int j = 0; j < 4; ++j)
            acc[i][j] += aa[i] * xx[j];
      }
    }
  }
  float* gp = Gpart + ((size_t)(tc * NB + b) * KC) * DD;
  #pragma unroll
  for (int i = 0; i < 4; ++i)
    #pragma unroll
    for (int j = 0; j < 4; ++j)
      gp[(ty * 4 + i) * DD + d0 + tx * 4 + j] = acc[i][j];
}

__global__ __launch_bounds__(256)
void finalize1_kernel(const float* __restrict__ Gpart, const float* __restrict__ S,
                      const float* __restrict__ centers, float* __restrict__ out,
                      float* __restrict__ bsum) {
  __shared__ float red[256];
  const int k = blockIdx.x, b = blockIdx.y, tid = threadIdx.x;
  const float sv = S[b * KC + k];
  float vals[2];
  float ss = 0.0f;
  #pragma unroll
  for (int r = 0; r < 2; ++r) {
    int d = tid + r * 256;
    float g = 0.0f;
    #pragma unroll
    for (int tc = 0; tc < 4; ++tc)
      g += Gpart[((size_t)(tc * NB + b) * KC + k) * DD + d];
    float v = g - sv * centers[k * DD + d];
    vals[r] = v; ss += v * v;
  }
  red[tid] = ss; __syncthreads();
  for (int st = 128; st > 0; st >>= 1) {
    if (tid < st) red[tid] += red[tid + st];
    __syncthreads();
  }
  float tot = red[0];
  float inv = 1.0f / fmaxf(sqrtf(tot), 1e-12f);
  #pragma unroll
  for (int r = 0; r < 2; ++r) {
    int d = tid + r * 256;
    out[(size_t)b * KC * DD + k * DD + d] = vals[r] * inv;
  }
  if (tid == 0) atomicAdd(&bsum[b], tot * inv * inv);
}

__global__ __launch_bounds__(256)
void finalize2_kernel(float* __restrict__ out, const float* __restrict__ bsum) {
  int idx = blockIdx.x * 256 + threadIdx.x;
  int b = idx >> 15;
  out[idx] = out[idx] / fmaxf(sqrtf(bsum[b]), 1e-12f);
}

// ---------------------------------------------------------------------------
extern "C" void kernel_launch(void* const* d_in, const int* in_sizes, int n_in,
                              void* d_out, int out_size, void* d_ws, size_t ws_size,
                              hipStream_t stream) {
  const float* x       = (const float*)d_in[0];
  const float* redu_w  = (const float*)d_in[1];
  const float* redu_b  = (const float*)d_in[2];
  const float* share_w = (const float*)d_in[3];
  const float* share_b = (const float*)d_in[4];
  const float* Uz      = (const float*)d_in[5];
  const float* Ur      = (const float*)d_in[6];
  const float* Uh      = (const float*)d_in[7];
  const float* centers = (const float*)d_in[8];
  float* out = (float*)d_out;

  float* wxbc = (float*)d_ws;                                // [col][64] f32; assignc overlay
  _Float16* xh = (_Float16*)(wxbc + (size_t)NCOL * KC);      // [col][1024] f16
  _Float16* a_f = xh;                                        // overlay, [n][p][k] f16
  _Float16* a_b = a_f + (size_t)NFR * HW * KC;
  _Float16* xrh = xh + (size_t)NCOL * CIN;                   // [col][512] f16
  float* Gpart = (float*)(xrh + (size_t)NCOL * DD);
  float* S = Gpart + (size_t)4 * NB * KC * DD;               // 512
  float* bsum = S + 512;                                     // 8
  _Float16* ufmt = (_Float16*)(bsum + 8);                    // 216*512 f16
  _Float16* wh = ufmt + 216 * 512;
  _Float16* swh = wh + (size_t)DD * CIN;
  float* assignc = wxbc;  // [n][p][k] f32 overlay (wxbc dead after GRU)

  hipMemsetAsync(bsum, 0, NB * sizeof(float), stream);
  hipMemsetAsync(S, 0, 512 * sizeof(float), stream);

  cvt_f16<<<dim3(512), 256, 0, stream>>>(redu_w, wh, DD * CIN);
  cvt_f16<<<dim3(32), 256, 0, stream>>>(share_w, swh, KC * DD);
  format_u<<<dim3(216), 64, 0, stream>>>(Uz, Ur, Uh, ufmt);
  transpose_x<<<dim3(16, 256), 256, 0, stream>>>(x, xh);

  // stage A: xrh[col][512] f16 = wh[512x1024] * xh^T
  gemm16<128, 4, true><<<dim3(392 * 4), 256, 0, stream>>>(
      wh, xh, redu_b, nullptr, xrh, DD, CIN);
  // stage B: wxbc[col][64] f32 = swh[64x512] * xrh^T
  gemm16<64, 1, false><<<dim3(392), 256, 0, stream>>>(
      swh, xrh, share_b, wxbc, nullptr, KC, DD);

  // GRU: 2-mi waves (1 bf read -> 4 MFMA in phase1), LDS state, VALU cuts
  gru_mfma8<<<dim3(16), 512, 0, stream>>>(wxbc, ufmt, a_f, a_b);

  softmax_kernel<<<dim3(196), 256, 0, stream>>>(a_f, a_b, assignc);
  sreduce_kernel<<<dim3(8, 8), 256, 0, stream>>>(assignc, S);
  vlad_gemm_kernel<<<dim3(8, 4, 8), 256, 0, stream>>>(assignc, xrh, Gpart);
  finalize1_kernel<<<dim3(64, 8), 256, 0, stream>>>(Gpart, S, centers, out, bsum);
  finalize2_kernel<<<dim3(1024), 256, 0, stream>>>(out, bsum);
}

// Round 13
// 864.221 us; speedup vs baseline: 1.7102x; 1.7102x over previous
//
#include <hip/hip_runtime.h>

#define HW 196
#define WIDTH 14
#define T_STEPS 32
#define KC 64      // centers / GRU channels
#define DD 512     // reduced dim
#define CIN 1024
#define NFR 256    // B*T
#define NB 8       // videos
#define NCOL (NFR * HW)   // 50176

using f16x8 = __attribute__((ext_vector_type(8))) _Float16;
using f16x4 = __attribute__((ext_vector_type(4))) _Float16;
using f32x4 = __attribute__((ext_vector_type(4))) float;

__device__ __forceinline__ void gload_lds16(const void* g, void* l) {
  __builtin_amdgcn_global_load_lds(
      (const __attribute__((address_space(1))) void*)g,
      (__attribute__((address_space(3))) void*)l, 16, 0, 0);
}

// fast sigmoid / tanh: v_exp_f32 + v_rcp_f32; exact saturation at +-inf.
// (validated rounds 7-10: absmax unchanged at 6.1e-5)
__device__ __forceinline__ float sigf(float x) {
  return __builtin_amdgcn_rcpf(1.0f + __expf(-x));
}
__device__ __forceinline__ float tanhfast(float x) {
  float e = __expf(2.0f * x);
  return 1.0f - 2.0f * __builtin_amdgcn_rcpf(e + 1.0f);
}

// ---------------------------------------------------------------------------
// f32 -> f16 elementwise convert (weights). nelem multiple of 4.
// ---------------------------------------------------------------------------
__global__ __launch_bounds__(256)
void cvt_f16(const float* __restrict__ src, _Float16* __restrict__ dst, int nelem) {
  int i = (blockIdx.x * 256 + threadIdx.x) * 4;
  if (i < nelem) {
    float4 v = *reinterpret_cast<const float4*>(src + i);
    f16x4 o;
    o[0] = (_Float16)v.x; o[1] = (_Float16)v.y;
    o[2] = (_Float16)v.z; o[3] = (_Float16)v.w;
    *reinterpret_cast<f16x4*>(dst + i) = o;
  }
}

// ---------------------------------------------------------------------------
// Transpose-convert x: (n, c, p) f32 -> xh[(n*196+p)][c] f16.
// Write path vectorized: f16x4 per lane (16 lanes x 4ch cover 64 ch; 16 p/pass).
// LDS read stride 4*197 f32 = 20 mod 32 banks -> worst 2-way (free).
// ---------------------------------------------------------------------------
__global__ __launch_bounds__(256)
void transpose_x(const float* __restrict__ x, _Float16* __restrict__ xh) {
  __shared__ float tile[64][197];
  const int tid = threadIdx.x;
  const int w = tid >> 6, lane = tid & 63;
  const int n = blockIdx.y;
  const int c0 = blockIdx.x * 64;
  const float* src = x + ((size_t)n * CIN + c0) * HW;
  for (int rr = 0; rr < 16; ++rr) {
    int c = w * 16 + rr;
    if (lane < 49) {
      float4 v = *reinterpret_cast<const float4*>(src + (size_t)c * HW + lane * 4);
      tile[c][lane * 4 + 0] = v.x; tile[c][lane * 4 + 1] = v.y;
      tile[c][lane * 4 + 2] = v.z; tile[c][lane * 4 + 3] = v.w;
    }
  }
  __syncthreads();
  _Float16* dst = xh + (size_t)n * HW * CIN + c0;
  #pragma unroll
  for (int pass = 0; pass < 13; ++pass) {
    int p = (tid >> 4) + pass * 16;
    int cg = (tid & 15) * 4;
    if (p < HW) {
      f16x4 v;
      #pragma unroll
      for (int j = 0; j < 4; ++j) v[j] = (_Float16)tile[cg + j][p];
      *reinterpret_cast<f16x4*>(dst + (size_t)p * CIN + cg) = v;
    }
  }
}

// ---------------------------------------------------------------------------
// f16 MFMA GEMM (validated round 4/5): out[m][col] = bias[m]+sum_k A[m][k]*B[col][k]
// WT: write outT[col][M] f16 (LDS-transposed) -- stage A.
// !WT: write outC[col][M] f32 (float4, k-contiguous) -- stage B.
// Block decode: mt = bx / nct, ct = bx % nct. With nct = 392 = 49*8 (mult of
// 8 XCDs), all NMT m-blocks of one col-tile share bx%8 -> SAME XCD -> the
// shared B tile is L2-served instead of 4x HBM-fetched.
// ---------------------------------------------------------------------------
template<int BM, int NMT, bool WT>
__global__ __launch_bounds__(256)
void gemm16(const _Float16* __restrict__ A, const _Float16* __restrict__ Bmat,
            const float* __restrict__ bias, float* __restrict__ outC,
            _Float16* __restrict__ outT, int M, int K) {
  constexpr int MF = BM / 32;
  union Smem {
    struct { _Float16 a[BM * 64]; _Float16 b[128 * 64]; } s;
    _Float16 t[WT ? 128 * 132 : 1];
  };
  __shared__ Smem u;

  const int tid = threadIdx.x;
  const int lane = tid & 63;
  const int w = tid >> 6;
  const int wm = w >> 1, wn = w & 1;
  const int l16 = lane & 15, lhi = lane >> 4;
  const int srow = lane >> 3, sslot = lane & 7;
  const int swz = (sslot ^ srow) << 4;
  const int nct = gridDim.x / NMT;
  const int mt = blockIdx.x / nct;
  const int ct = blockIdx.x - mt * nct;
  const int m0 = mt * BM;
  const int col0 = ct * 128;

  f32x4 acc[MF][4];
  #pragma unroll
  for (int i = 0; i < MF; ++i)
    #pragma unroll
    for (int f = 0; f < 4; ++f) acc[i][f] = {0.f, 0.f, 0.f, 0.f};

  for (int k0 = 0; k0 < K; k0 += 64) {
    #pragma unroll
    for (int s = 0; s < BM / 32; ++s) {
      int r = w * (BM / 4) + s * 8;
      gload_lds16((const char*)(A + (size_t)(m0 + r + srow) * K + k0) + swz,
                  (char*)u.s.a + r * 128);
    }
    #pragma unroll
    for (int s = 0; s < 4; ++s) {
      int r = w * 32 + s * 8;
      gload_lds16((const char*)(Bmat + (size_t)(col0 + r + srow) * K + k0) + swz,
                  (char*)u.s.b + r * 128);
    }
    __syncthreads();
    #pragma unroll
    for (int kk = 0; kk < 2; ++kk) {
      f16x8 af[MF];
      #pragma unroll
      for (int i = 0; i < MF; ++i) {
        int row = wm * (MF * 16) + i * 16 + l16;
        af[i] = *reinterpret_cast<const f16x8*>(
            (const char*)u.s.a + row * 128 + ((kk * 64 + lhi * 16) ^ ((row & 7) << 4)));
      }
      #pragma unroll
      for (int f = 0; f < 4; ++f) {
        int row = wn * 64 + f * 16 + l16;
        f16x8 bf = *reinterpret_cast<const f16x8*>(
            (const char*)u.s.b + row * 128 + ((kk * 64 + lhi * 16) ^ ((row & 7) << 4)));
        #pragma unroll
        for (int i = 0; i < MF; ++i)
          acc[i][f] = __builtin_amdgcn_mfma_f32_16x16x32_f16(af[i], bf, acc[i][f], 0, 0, 0);
      }
    }
    __syncthreads();
  }

  if constexpr (!WT) {
    #pragma unroll
    for (int i = 0; i < MF; ++i) {
      int m = m0 + wm * (MF * 16) + i * 16 + lhi * 4;
      float b0 = bias[m], b1 = bias[m + 1], b2 = bias[m + 2], b3 = bias[m + 3];
      #pragma unroll
      for (int f = 0; f < 4; ++f) {
        int col = col0 + wn * 64 + f * 16 + l16;
        float4 o = {acc[i][f][0] + b0, acc[i][f][1] + b1,
                    acc[i][f][2] + b2, acc[i][f][3] + b3};
        *reinterpret_cast<float4*>(outC + (size_t)col * M + m) = o;
      }
    }
  } else {
    #pragma unroll
    for (int i = 0; i < MF; ++i) {
      int ml = wm * (MF * 16) + i * 16 + lhi * 4;
      int m = m0 + ml;
      float b0 = bias[m], b1 = bias[m + 1], b2 = bias[m + 2], b3 = bias[m + 3];
      #pragma unroll
      for (int f = 0; f < 4; ++f) {
        int cl = wn * 64 + f * 16 + l16;
        f16x4 v;
        v[0] = (_Float16)(acc[i][f][0] + b0);
        v[1] = (_Float16)(acc[i][f][1] + b1);
        v[2] = (_Float16)(acc[i][f][2] + b2);
        v[3] = (_Float16)(acc[i][f][3] + b3);
        *reinterpret_cast<f16x4*>((char*)u.t + cl * 264 + ml * 2) = v;
      }
    }
    __syncthreads();
    #pragma unroll
    for (int pass = 0; pass < 16; ++pass) {
      int row = (tid >> 5) + pass * 8;
      int coff = (tid & 31) * 4;
      f16x4 v = *reinterpret_cast<const f16x4*>((const char*)u.t + row * 264 + coff * 2);
      *reinterpret_cast<f16x4*>(outT + (size_t)(col0 + row) * M + m0 + coff) = v;
    }
  }
}

// ---------------------------------------------------------------------------
// Pre-format U weights into MFMA A-fragments (validated round 3).
// ---------------------------------------------------------------------------
__global__ __launch_bounds__(64)
void format_u(const float* __restrict__ Uz, const float* __restrict__ Ur,
              const float* __restrict__ Uh, _Float16* __restrict__ ufmt) {
  const int f = blockIdx.x;        // 0..215
  const int lane = threadIdx.x;
  const int l16 = lane & 15;
  const float* U;
  int ch, kt;
  if (f < 144) {
    int pair = f / 36, rem = f - pair * 36;
    int mi = rem / 18; kt = rem - mi * 18;
    U = (pair < 2) ? Uz : Ur;
    ch = (pair & 1) * 32 + mi * 16 + l16;
  } else {
    int g = f - 144;
    int pair = g / 36, rem = g - pair * 36;
    int mi = rem / 18; kt = rem - mi * 18;
    U = Uh;
    ch = pair * 32 + mi * 16 + l16;
  }
  const int tap = kt >> 1;
  const int k0 = (kt & 1) * 32 + (lane >> 4) * 8;
  f16x8 v;
  #pragma unroll
  for (int j = 0; j < 8; ++j)
    v[j] = (_Float16)U[(size_t)ch * 576 + (k0 + j) * 9 + tap];
  *reinterpret_cast<f16x8*>(ufmt + (size_t)f * 512 + lane * 8) = v;
}

// ---------------------------------------------------------------------------
// GRU v6 (EXACT round-10 kernel, proven 443 us): 512 thr, 8 waves, VGPR 128
// no-spill, z in LDS zbuf / h in LDS h32, af arrays (2 streams max!)
// rematerialized by compiler from L2, fast activations, precomputed swizzle
// bases. Wave = (mi = w&3, half = w>>2). DO NOT move af loads into the kt
// loop or add streams: >2 af streams at 128 VGPR = per-MFMA L2 stall
// (round-11 failure, 1055us); persistent reg state = spill (rounds 7-9).
// ---------------------------------------------------------------------------
__global__ __launch_bounds__(512, 2)
void gru_mfma8(const float* __restrict__ wxbc, const _Float16* __restrict__ ufmt,
               _Float16* __restrict__ a_f, _Float16* __restrict__ a_b) {
  __shared__ __align__(16) _Float16 hpad[256 * 64];   // 32KB padded h (swizzled)
  __shared__ __align__(16) _Float16 rhpad[256 * 64];  // 32KB padded r*h
  __shared__ __align__(16) _Float16 zbuf[208 * 64];   // 26.6KB z (swizzled)
  __shared__ __align__(16) float h32[HW * 68];        // 52KB fp32 h, padded rows

  const int tid = threadIdx.x;
  const int lane = tid & 63;
  const int w = tid >> 6;            // wave 0..7
  const int l16 = lane & 15, lhi = lane >> 4;
  const int chain = blockIdx.x;
  const int b = chain >> 1, dir = chain & 1;
  const int mi = w & 3;
  const int half = w >> 2;
  const int ntb = half * 7;          // base pixel-tile
  const int ntn = half ? 6 : 7;      // tiles owned
  const int ch0 = mi * 16 + lhi * 4;
  const int chlo = lhi * 16, chhi = 64 + lhi * 16;

  for (int i = tid; i < 256 * 64; i += 512) { hpad[i] = (_Float16)0.f; rhpad[i] = (_Float16)0.f; }
  for (int i = tid; i < HW * 68; i += 512) h32[i] = 0.0f;
  __syncthreads();

  _Float16* adest = dir ? a_b : a_f;
  const char* hpadB = reinterpret_cast<const char*>(hpad);
  const char* rhpadB = reinterpret_cast<const char*>(rhpad);
  const _Float16* uf = ufmt + (size_t)lane * 8;
  const int fz0 = (mi >> 1) * 36 + (mi & 1) * 18;   // z frag base for this mi

  for (int t = 0; t < T_STEPS; ++t) {
    const int tw = dir ? (T_STEPS - 1 - t) : t;
    const float* wtc = wxbc + (size_t)(b * T_STEPS + tw) * HW * KC;

    // ================= phase 1: z -> zbuf, r*h -> rhpad ====================
    {
      f16x8 afz[18], afr[18];
      #pragma unroll
      for (int kt = 0; kt < 18; ++kt) {
        afz[kt] = *reinterpret_cast<const f16x8*>(uf + (size_t)(fz0 + kt) * 512);
        afr[kt] = *reinterpret_cast<const f16x8*>(uf + (size_t)(fz0 + 72 + kt) * 512);
      }
      for (int i = 0; i < ntn; ++i) {
        const int nt = ntb + i;
        const int p = nt * 16 + l16;
        const bool act = p < HW;
        const int pc = act ? p : (HW - 1);
        const int py = pc / 14, px_ = pc - py * 14;
        const int base0 = py * 16 + px_;
        const int tb = base0 * 128;
        const int rb0 = tb +       (chlo ^ ((px_ & 7) << 4));
        const int rb1 = tb + 128 + (chlo ^ (((px_ + 1) & 7) << 4));
        const int rb2 = tb + 256 + (chlo ^ (((px_ + 2) & 7) << 4));
        const int rb3 = tb +       (chhi ^ ((px_ & 7) << 4));
        const int rb4 = tb + 128 + (chhi ^ (((px_ + 1) & 7) << 4));
        const int rb5 = tb + 256 + (chhi ^ (((px_ + 2) & 7) << 4));
        const float4 wt4 = *reinterpret_cast<const float4*>(wtc + (size_t)pc * KC + ch0);
        f32x4 az = {0.f, 0.f, 0.f, 0.f};
        f32x4 ar = {0.f, 0.f, 0.f, 0.f};
        #pragma unroll
        for (int kt = 0; kt < 18; ++kt) {
          const int tap = kt >> 1, dy = tap / 3, dx = tap - dy * 3;
          const int base = (kt & 1) ? (dx == 0 ? rb3 : dx == 1 ? rb4 : rb5)
                                    : (dx == 0 ? rb0 : dx == 1 ? rb1 : rb2);
          const f16x8 bf = *reinterpret_cast<const f16x8*>(hpadB + base + dy * 2048);
          az = __builtin_amdgcn_mfma_f32_16x16x32_f16(afz[kt], bf, az, 0, 0, 0);
          ar = __builtin_amdgcn_mfma_f32_16x16x32_f16(afr[kt], bf, ar, 0, 0, 0);
        }
        if (act) {
          const float wta[4] = {wt4.x, wt4.y, wt4.z, wt4.w};
          const float4 hv = *reinterpret_cast<const float4*>(&h32[pc * 68 + ch0]);
          const float hva[4] = {hv.x, hv.y, hv.z, hv.w};
          f16x4 zw, rhw;
          #pragma unroll
          for (int jj = 0; jj < 4; ++jj) {
            float z = sigf(az[jj] + wta[jj]);
            float r = sigf(ar[jj] + wta[jj]);
            zw[jj] = (_Float16)z;
            rhw[jj] = (_Float16)(r * hva[jj]);
          }
          *reinterpret_cast<f16x4*>(reinterpret_cast<char*>(zbuf) +
              p * 128 + ((ch0 * 2) ^ ((p & 7) << 4))) = zw;
          const int ppw = base0 + 17;
          *reinterpret_cast<f16x4*>(reinterpret_cast<char*>(rhpad) +
              ppw * 128 + ((ch0 * 2) ^ ((ppw & 7) << 4))) = rhw;
        }
      }
    }
    __syncthreads();

    // ================= phase 2: hh = tanh(wt + conv(rh,Uh)); update h ======
    {
      _Float16* ad = adest + (size_t)(b * T_STEPS + tw) * HW * KC;
      f16x8 afh[18];
      #pragma unroll
      for (int kt = 0; kt < 18; ++kt)
        afh[kt] = *reinterpret_cast<const f16x8*>(uf + (size_t)(144 + fz0 + kt) * 512);
      for (int i = 0; i < ntn; ++i) {
        const int nt = ntb + i;
        const int p = nt * 16 + l16;
        const bool act = p < HW;
        const int pc = act ? p : (HW - 1);
        const int py = pc / 14, px_ = pc - py * 14;
        const int base0 = py * 16 + px_;
        const int tb = base0 * 128;
        const int rb0 = tb +       (chlo ^ ((px_ & 7) << 4));
        const int rb1 = tb + 128 + (chlo ^ (((px_ + 1) & 7) << 4));
        const int rb2 = tb + 256 + (chlo ^ (((px_ + 2) & 7) << 4));
        const int rb3 = tb +       (chhi ^ ((px_ & 7) << 4));
        const int rb4 = tb + 128 + (chhi ^ (((px_ + 1) & 7) << 4));
        const int rb5 = tb + 256 + (chhi ^ (((px_ + 2) & 7) << 4));
        const float4 wt4 = *reinterpret_cast<const float4*>(wtc + (size_t)pc * KC + ch0);
        f32x4 ah = {0.f, 0.f, 0.f, 0.f};
        #pragma unroll
        for (int kt = 0; kt < 18; ++kt) {
          const int tap = kt >> 1, dy = tap / 3, dx = tap - dy * 3;
          const int base = (kt & 1) ? (dx == 0 ? rb3 : dx == 1 ? rb4 : rb5)
                                    : (dx == 0 ? rb0 : dx == 1 ? rb1 : rb2);
          const f16x8 bf = *reinterpret_cast<const f16x8*>(rhpadB + base + dy * 2048);
          ah = __builtin_amdgcn_mfma_f32_16x16x32_f16(afh[kt], bf, ah, 0, 0, 0);
        }
        if (act) {
          const float wta[4] = {wt4.x, wt4.y, wt4.z, wt4.w};
          const f16x4 zv = *reinterpret_cast<const f16x4*>(
              reinterpret_cast<const char*>(zbuf) + p * 128 + ((ch0 * 2) ^ ((p & 7) << 4)));
          const float4 hv = *reinterpret_cast<const float4*>(&h32[pc * 68 + ch0]);
          const float hva[4] = {hv.x, hv.y, hv.z, hv.w};
          f16x4 hw;
          float hna[4];
          #pragma unroll
          for (int jj = 0; jj < 4; ++jj) {
            float hh = tanhfast(ah[jj] + wta[jj]);
            float z = (float)zv[jj];
            float hn = hh + z * (hva[jj] - hh);   // (1-z)*hh + z*h
            hna[jj] = hn;
            hw[jj] = (_Float16)hn;
          }
          float4 hn4 = {hna[0], hna[1], hna[2], hna[3]};
          *reinterpret_cast<float4*>(&h32[pc * 68 + ch0]) = hn4;
          const int ppw = base0 + 17;
          *reinterpret_cast<f16x4*>(reinterpret_cast<char*>(hpad) +
              ppw * 128 + ((ch0 * 2) ^ ((ppw & 7) << 4))) = hw;
          *reinterpret_cast<f16x4*>(ad + (size_t)pc * KC + ch0) = hw;
        }
      }
    }
    __syncthreads();
  }
}

// ---------------------------------------------------------------------------
// softmax over K=64 per pixel-row; logits = a_f + a_b (f16, [n][p][k]),
// output f32 [n][p][k].
// ---------------------------------------------------------------------------
__global__ __launch_bounds__(256)
void softmax_kernel(const _Float16* __restrict__ af, const _Float16* __restrict__ ab,
                    float* __restrict__ out) {
  size_t idx = (size_t)blockIdx.x * 256 + threadIdx.x;   // 0..50175
  const _Float16* cf = af + idx * KC;
  const _Float16* cb = ab + idx * KC;
  float* co = out + idx * KC;
  float v[KC];
  float mx = -3.4e38f;
  #pragma unroll
  for (int g = 0; g < 8; ++g) {
    f16x8 a = *reinterpret_cast<const f16x8*>(cf + g * 8);
    f16x8 bq = *reinterpret_cast<const f16x8*>(cb + g * 8);
    #pragma unroll
    for (int j = 0; j < 8; ++j) {
      float s = (float)a[j] + (float)bq[j];
      v[g * 8 + j] = s;
      mx = fmaxf(mx, s);
    }
  }
  float ssum = 0.0f;
  #pragma unroll
  for (int k = 0; k < KC; ++k) { v[k] = expf(v[k] - mx); ssum += v[k]; }
  float inv = 1.0f / ssum;
  #pragma unroll
  for (int g = 0; g < 16; ++g) {
    float4 o = {v[g * 4] * inv, v[g * 4 + 1] * inv, v[g * 4 + 2] * inv, v[g * 4 + 3] * inv};
    *reinterpret_cast<float4*>(co + g * 4) = o;
  }
}

// ---------------------------------------------------------------------------
// S[b][k] = sum over (t,p) of assign ([n][p][k] layout). grid (8 seg, 8 b).
// ---------------------------------------------------------------------------
__global__ __launch_bounds__(256)
void sreduce_kernel(const float* __restrict__ a, float* __restrict__ S) {
  __shared__ float red[4][64];
  const int seg = blockIdx.x, b = blockIdx.y, tid = threadIdx.x;
  const int k = tid & 63, rg = tid >> 6;
  const float* base = a + (size_t)b * T_STEPS * HW * KC;
  float sum = 0.0f;
  for (int rr = seg * 784 + rg; rr < (seg + 1) * 784; rr += 4)
    sum += base[(size_t)rr * KC + k];
  red[rg][k] = sum;
  __syncthreads();
  if (tid < 64) {
    float s = red[0][k] + red[1][k] + red[2][k] + red[3][k];
    atomicAdd(&S[b * KC + k], s);
  }
}

// ---------------------------------------------------------------------------
// VLAD GEMM partials; assign [n][p][k] f32, xrh [n*196+p][512] f16.
// ---------------------------------------------------------------------------
__global__ __launch_bounds__(256)
void vlad_gemm_kernel(const float* __restrict__ a, const _Float16* __restrict__ xrh,
                      float* __restrict__ Gpart) {
  __shared__ float sA[16][68];
  __shared__ float sX[16][68];
  const int tid = threadIdx.x;
  const int tx = tid & 15, ty = tid >> 4;
  const int d0 = blockIdx.x * 64;
  const int tc = blockIdx.y;
  const int b  = blockIdx.z;
  const int kk = tid & 63, pj = tid >> 6;
  float acc[4][4] = {};

  for (int tt = 0; tt < 8; ++tt) {
    int n = b * T_STEPS + tc * 8 + tt;
    const float* an = a + (size_t)n * HW * KC;
    const _Float16* xn = xrh + (size_t)n * HW * DD;
    for (int p0 = 0; p0 < HW; p0 += 16) {
      __syncthreads();
      #pragma unroll
      for (int j = 0; j < 4; ++j) {
        int pl = pj * 4 + j;
        int p = p0 + pl;
        sA[pl][kk] = (p < HW) ? an[(size_t)p * KC + kk] : 0.0f;
        sX[pl][kk] = (p < HW) ? (float)xn[(size_t)p * DD + d0 + kk] : 0.0f;
      }
      __syncthreads();
      #pragma unroll
      for (int pp = 0; pp < 16; ++pp) {
        float4 av = *reinterpret_cast<const float4*>(&sA[pp][ty * 4]);
        float4 xv = *reinterpret_cast<const float4*>(&sX[pp][tx * 4]);
        float aa[4] = {av.x, av.y, av.z, av.w};
        float xx[4] = {xv.x, xv.y, xv.z, xv.w};
        #pragma unroll
        for (int i = 0; i < 4; ++i)
          #pragma unroll
          for (int j = 0; j < 4; ++j)
            acc[i][j] += aa[i] * xx[j];
      }
    }
  }
  float* gp = Gpart + ((size_t)(tc * NB + b) * KC) * DD;
  #pragma unroll
  for (int i = 0; i < 4; ++i)
    #pragma unroll
    for (int j = 0; j < 4; ++j)
      gp[(ty * 4 + i) * DD + d0 + tx * 4 + j] = acc[i][j];
}

__global__ __launch_bounds__(256)
void finalize1_kernel(const float* __restrict__ Gpart, const float* __restrict__ S,
                      const float* __restrict__ centers, float* __restrict__ out,
                      float* __restrict__ bsum) {
  __shared__ float red[256];
  const int k = blockIdx.x, b = blockIdx.y, tid = threadIdx.x;
  const float sv = S[b * KC + k];
  float vals[2];
  float ss = 0.0f;
  #pragma unroll
  for (int r = 0; r < 2; ++r) {
    int d = tid + r * 256;
    float g = 0.0f;
    #pragma unroll
    for (int tc = 0; tc < 4; ++tc)
      g += Gpart[((size_t)(tc * NB + b) * KC + k) * DD + d];
    float v = g - sv * centers[k * DD + d];
    vals[r] = v; ss += v * v;
  }
  red[tid] = ss; __syncthreads();
  for (int st = 128; st > 0; st >>= 1) {
    if (tid < st) red[tid] += red[tid + st];
    __syncthreads();
  }
  float tot = red[0];
  float inv = 1.0f / fmaxf(sqrtf(tot), 1e-12f);
  #pragma unroll
  for (int r = 0; r < 2; ++r) {
    int d = tid + r * 256;
    out[(size_t)b * KC * DD + k * DD + d] = vals[r] * inv;
  }
  if (tid == 0) atomicAdd(&bsum[b], tot * inv * inv);
}

__global__ __launch_bounds__(256)
void finalize2_kernel(float* __restrict__ out, const float* __restrict__ bsum) {
  int idx = blockIdx.x * 256 + threadIdx.x;
  int b = idx >> 15;
  out[idx] = out[idx] / fmaxf(sqrtf(bsum[b]), 1e-12f);
}

// ---------------------------------------------------------------------------
extern "C" void kernel_launch(void* const* d_in, const int* in_sizes, int n_in,
                              void* d_out, int out_size, void* d_ws, size_t ws_size,
                              hipStream_t stream) {
  const float* x       = (const float*)d_in[0];
  const float* redu_w  = (const float*)d_in[1];
  const float* redu_b  = (const float*)d_in[2];
  const float* share_w = (const float*)d_in[3];
  const float* share_b = (const float*)d_in[4];
  const float* Uz      = (const float*)d_in[5];
  const float* Ur      = (const float*)d_in[6];
  const float* Uh      = (const float*)d_in[7];
  const float* centers = (const float*)d_in[8];
  float* out = (float*)d_out;

  float* wxbc = (float*)d_ws;                                // [col][64] f32; assignc overlay
  _Float16* xh = (_Float16*)(wxbc + (size_t)NCOL * KC);      // [col][1024] f16
  _Float16* a_f = xh;                                        // overlay, [n][p][k] f16
  _Float16* a_b = a_f + (size_t)NFR * HW * KC;
  _Float16* xrh = xh + (size_t)NCOL * CIN;                   // [col][512] f16
  float* Gpart = (float*)(xrh + (size_t)NCOL * DD);
  float* S = Gpart + (size_t)4 * NB * KC * DD;               // 512
  float* bsum = S + 512;                                     // 8
  _Float16* ufmt = (_Float16*)(bsum + 8);                    // 216*512 f16
  _Float16* wh = ufmt + 216 * 512;
  _Float16* swh = wh + (size_t)DD * CIN;
  float* assignc = wxbc;  // [n][p][k] f32 overlay (wxbc dead after GRU)

  hipMemsetAsync(bsum, 0, NB * sizeof(float), stream);
  hipMemsetAsync(S, 0, 512 * sizeof(float), stream);

  cvt_f16<<<dim3(512), 256, 0, stream>>>(redu_w, wh, DD * CIN);
  cvt_f16<<<dim3(32), 256, 0, stream>>>(share_w, swh, KC * DD);
  format_u<<<dim3(216), 64, 0, stream>>>(Uz, Ur, Uh, ufmt);
  transpose_x<<<dim3(16, 256), 256, 0, stream>>>(x, xh);

  // stage A: xrh[col][512] f16 = wh[512x1024] * xh^T (mt-grouped XCD decode)
  gemm16<128, 4, true><<<dim3(392 * 4), 256, 0, stream>>>(
      wh, xh, redu_b, nullptr, xrh, DD, CIN);
  // stage B: wxbc[col][64] f32 = swh[64x512] * xrh^T
  gemm16<64, 1, false><<<dim3(392), 256, 0, stream>>>(
      swh, xrh, share_b, wxbc, nullptr, KC, DD);

  // GRU: round-10 proven kernel (443 us)
  gru_mfma8<<<dim3(16), 512, 0, stream>>>(wxbc, ufmt, a_f, a_b);

  softmax_kernel<<<dim3(196), 256, 0, stream>>>(a_f, a_b, assignc);
  sreduce_kernel<<<dim3(8, 8), 256, 0, stream>>>(assignc, S);
  vlad_gemm_kernel<<<dim3(8, 4, 8), 256, 0, stream>>>(assignc, xrh, Gpart);
  finalize1_kernel<<<dim3(64, 8), 256, 0, stream>>>(Gpart, S, centers, out, bsum);
  finalize2_kernel<<<dim3(1024), 256, 0, stream>>>(out, bsum);
}

// Round 14
// 776.214 us; speedup vs baseline: 1.9041x; 1.1134x over previous
//
#include <hip/hip_runtime.h>

#define HW 196
#define WIDTH 14
#define T_STEPS 32
#define KC 64      // centers / GRU channels
#define DD 512     // reduced dim
#define CIN 1024
#define NFR 256    // B*T
#define NB 8       // videos
#define NCOL (NFR * HW)   // 50176

using f16x8 = __attribute__((ext_vector_type(8))) _Float16;
using f16x4 = __attribute__((ext_vector_type(4))) _Float16;
using f32x4 = __attribute__((ext_vector_type(4))) float;

__device__ __forceinline__ void gload_lds16(const void* g, void* l) {
  __builtin_amdgcn_global_load_lds(
      (const __attribute__((address_space(1))) void*)g,
      (__attribute__((address_space(3))) void*)l, 16, 0, 0);
}

// fast sigmoid / tanh: v_exp_f32 + v_rcp_f32; exact saturation at +-inf.
__device__ __forceinline__ float sigf(float x) {
  return __builtin_amdgcn_rcpf(1.0f + __expf(-x));
}
__device__ __forceinline__ float tanhfast(float x) {
  float e = __expf(2.0f * x);
  return 1.0f - 2.0f * __builtin_amdgcn_rcpf(e + 1.0f);
}

// ---------------------------------------------------------------------------
// f32 -> f16 elementwise convert (weights).
// ---------------------------------------------------------------------------
__global__ __launch_bounds__(256)
void cvt_f16(const float* __restrict__ src, _Float16* __restrict__ dst, int nelem) {
  int i = (blockIdx.x * 256 + threadIdx.x) * 4;
  if (i < nelem) {
    float4 v = *reinterpret_cast<const float4*>(src + i);
    f16x4 o;
    o[0] = (_Float16)v.x; o[1] = (_Float16)v.y;
    o[2] = (_Float16)v.z; o[3] = (_Float16)v.w;
    *reinterpret_cast<f16x4*>(dst + i) = o;
  }
}

// ---------------------------------------------------------------------------
// Transpose-convert x: (n, c, p) f32 -> xh[(n*196+p)][c] f16.
// ---------------------------------------------------------------------------
__global__ __launch_bounds__(256)
void transpose_x(const float* __restrict__ x, _Float16* __restrict__ xh) {
  __shared__ float tile[64][197];
  const int tid = threadIdx.x;
  const int w = tid >> 6, lane = tid & 63;
  const int n = blockIdx.y;
  const int c0 = blockIdx.x * 64;
  const float* src = x + ((size_t)n * CIN + c0) * HW;
  for (int rr = 0; rr < 16; ++rr) {
    int c = w * 16 + rr;
    if (lane < 49) {
      float4 v = *reinterpret_cast<const float4*>(src + (size_t)c * HW + lane * 4);
      tile[c][lane * 4 + 0] = v.x; tile[c][lane * 4 + 1] = v.y;
      tile[c][lane * 4 + 2] = v.z; tile[c][lane * 4 + 3] = v.w;
    }
  }
  __syncthreads();
  _Float16* dst = xh + (size_t)n * HW * CIN + c0;
  #pragma unroll
  for (int pass = 0; pass < 13; ++pass) {
    int p = (tid >> 4) + pass * 16;
    int cg = (tid & 15) * 4;
    if (p < HW) {
      f16x4 v;
      #pragma unroll
      for (int j = 0; j < 4; ++j) v[j] = (_Float16)tile[cg + j][p];
      *reinterpret_cast<f16x4*>(dst + (size_t)p * CIN + cg) = v;
    }
  }
}

// ---------------------------------------------------------------------------
// f16 MFMA GEMM (validated rounds 4-12).
// ---------------------------------------------------------------------------
template<int BM, int NMT, bool WT>
__global__ __launch_bounds__(256)
void gemm16(const _Float16* __restrict__ A, const _Float16* __restrict__ Bmat,
            const float* __restrict__ bias, float* __restrict__ outC,
            _Float16* __restrict__ outT, int M, int K) {
  constexpr int MF = BM / 32;
  union Smem {
    struct { _Float16 a[BM * 64]; _Float16 b[128 * 64]; } s;
    _Float16 t[WT ? 128 * 132 : 1];
  };
  __shared__ Smem u;

  const int tid = threadIdx.x;
  const int lane = tid & 63;
  const int w = tid >> 6;
  const int wm = w >> 1, wn = w & 1;
  const int l16 = lane & 15, lhi = lane >> 4;
  const int srow = lane >> 3, sslot = lane & 7;
  const int swz = (sslot ^ srow) << 4;
  const int nct = gridDim.x / NMT;
  const int mt = blockIdx.x / nct;
  const int ct = blockIdx.x - mt * nct;
  const int m0 = mt * BM;
  const int col0 = ct * 128;

  f32x4 acc[MF][4];
  #pragma unroll
  for (int i = 0; i < MF; ++i)
    #pragma unroll
    for (int f = 0; f < 4; ++f) acc[i][f] = {0.f, 0.f, 0.f, 0.f};

  for (int k0 = 0; k0 < K; k0 += 64) {
    #pragma unroll
    for (int s = 0; s < BM / 32; ++s) {
      int r = w * (BM / 4) + s * 8;
      gload_lds16((const char*)(A + (size_t)(m0 + r + srow) * K + k0) + swz,
                  (char*)u.s.a + r * 128);
    }
    #pragma unroll
    for (int s = 0; s < 4; ++s) {
      int r = w * 32 + s * 8;
      gload_lds16((const char*)(Bmat + (size_t)(col0 + r + srow) * K + k0) + swz,
                  (char*)u.s.b + r * 128);
    }
    __syncthreads();
    #pragma unroll
    for (int kk = 0; kk < 2; ++kk) {
      f16x8 af[MF];
      #pragma unroll
      for (int i = 0; i < MF; ++i) {
        int row = wm * (MF * 16) + i * 16 + l16;
        af[i] = *reinterpret_cast<const f16x8*>(
            (const char*)u.s.a + row * 128 + ((kk * 64 + lhi * 16) ^ ((row & 7) << 4)));
      }
      #pragma unroll
      for (int f = 0; f < 4; ++f) {
        int row = wn * 64 + f * 16 + l16;
        f16x8 bf = *reinterpret_cast<const f16x8*>(
            (const char*)u.s.b + row * 128 + ((kk * 64 + lhi * 16) ^ ((row & 7) << 4)));
        #pragma unroll
        for (int i = 0; i < MF; ++i)
          acc[i][f] = __builtin_amdgcn_mfma_f32_16x16x32_f16(af[i], bf, acc[i][f], 0, 0, 0);
      }
    }
    __syncthreads();
  }

  if constexpr (!WT) {
    #pragma unroll
    for (int i = 0; i < MF; ++i) {
      int m = m0 + wm * (MF * 16) + i * 16 + lhi * 4;
      float b0 = bias[m], b1 = bias[m + 1], b2 = bias[m + 2], b3 = bias[m + 3];
      #pragma unroll
      for (int f = 0; f < 4; ++f) {
        int col = col0 + wn * 64 + f * 16 + l16;
        float4 o = {acc[i][f][0] + b0, acc[i][f][1] + b1,
                    acc[i][f][2] + b2, acc[i][f][3] + b3};
        *reinterpret_cast<float4*>(outC + (size_t)col * M + m) = o;
      }
    }
  } else {
    #pragma unroll
    for (int i = 0; i < MF; ++i) {
      int ml = wm * (MF * 16) + i * 16 + lhi * 4;
      int m = m0 + ml;
      float b0 = bias[m], b1 = bias[m + 1], b2 = bias[m + 2], b3 = bias[m + 3];
      #pragma unroll
      for (int f = 0; f < 4; ++f) {
        int cl = wn * 64 + f * 16 + l16;
        f16x4 v;
        v[0] = (_Float16)(acc[i][f][0] + b0);
        v[1] = (_Float16)(acc[i][f][1] + b1);
        v[2] = (_Float16)(acc[i][f][2] + b2);
        v[3] = (_Float16)(acc[i][f][3] + b3);
        *reinterpret_cast<f16x4*>((char*)u.t + cl * 264 + ml * 2) = v;
      }
    }
    __syncthreads();
    #pragma unroll
    for (int pass = 0; pass < 16; ++pass) {
      int row = (tid >> 5) + pass * 8;
      int coff = (tid & 31) * 4;
      f16x4 v = *reinterpret_cast<const f16x4*>((const char*)u.t + row * 264 + coff * 2);
      *reinterpret_cast<f16x4*>(outT + (size_t)(col0 + row) * M + m0 + coff) = v;
    }
  }
}

// ---------------------------------------------------------------------------
// Pre-format U weights into MFMA A-fragments (validated round 3).
// ---------------------------------------------------------------------------
__global__ __launch_bounds__(64)
void format_u(const float* __restrict__ Uz, const float* __restrict__ Ur,
              const float* __restrict__ Uh, _Float16* __restrict__ ufmt) {
  const int f = blockIdx.x;        // 0..215
  const int lane = threadIdx.x;
  const int l16 = lane & 15;
  const float* U;
  int ch, kt;
  if (f < 144) {
    int pair = f / 36, rem = f - pair * 36;
    int mi = rem / 18; kt = rem - mi * 18;
    U = (pair < 2) ? Uz : Ur;
    ch = (pair & 1) * 32 + mi * 16 + l16;
  } else {
    int g = f - 144;
    int pair = g / 36, rem = g - pair * 36;
    int mi = rem / 18; kt = rem - mi * 18;
    U = Uh;
    ch = pair * 32 + mi * 16 + l16;
  }
  const int tap = kt >> 1;
  const int k0 = (kt & 1) * 32 + (lane >> 4) * 8;
  f16x8 v;
  #pragma unroll
  for (int j = 0; j < 8; ++j)
    v[j] = (_Float16)U[(size_t)ch * 576 + (k0 + j) * 9 + tap];
  *reinterpret_cast<f16x8*>(ufmt + (size_t)f * 512 + lane * 8) = v;
}

// ---------------------------------------------------------------------------
// GRU (EXACT round-10/12 kernel, proven 443 us). DO NOT add af streams (>2 =
// per-MFMA L2 stall, round 11) or persistent register state (= spill, r7-9).
// ---------------------------------------------------------------------------
__global__ __launch_bounds__(512, 2)
void gru_mfma8(const float* __restrict__ wxbc, const _Float16* __restrict__ ufmt,
               _Float16* __restrict__ a_f, _Float16* __restrict__ a_b) {
  __shared__ __align__(16) _Float16 hpad[256 * 64];   // 32KB padded h (swizzled)
  __shared__ __align__(16) _Float16 rhpad[256 * 64];  // 32KB padded r*h
  __shared__ __align__(16) _Float16 zbuf[208 * 64];   // 26.6KB z (swizzled)
  __shared__ __align__(16) float h32[HW * 68];        // 52KB fp32 h, padded rows

  const int tid = threadIdx.x;
  const int lane = tid & 63;
  const int w = tid >> 6;            // wave 0..7
  const int l16 = lane & 15, lhi = lane >> 4;
  const int chain = blockIdx.x;
  const int b = chain >> 1, dir = chain & 1;
  const int mi = w & 3;
  const int half = w >> 2;
  const int ntb = half * 7;          // base pixel-tile
  const int ntn = half ? 6 : 7;      // tiles owned
  const int ch0 = mi * 16 + lhi * 4;
  const int chlo = lhi * 16, chhi = 64 + lhi * 16;

  for (int i = tid; i < 256 * 64; i += 512) { hpad[i] = (_Float16)0.f; rhpad[i] = (_Float16)0.f; }
  for (int i = tid; i < HW * 68; i += 512) h32[i] = 0.0f;
  __syncthreads();

  _Float16* adest = dir ? a_b : a_f;
  const char* hpadB = reinterpret_cast<const char*>(hpad);
  const char* rhpadB = reinterpret_cast<const char*>(rhpad);
  const _Float16* uf = ufmt + (size_t)lane * 8;
  const int fz0 = (mi >> 1) * 36 + (mi & 1) * 18;

  for (int t = 0; t < T_STEPS; ++t) {
    const int tw = dir ? (T_STEPS - 1 - t) : t;
    const float* wtc = wxbc + (size_t)(b * T_STEPS + tw) * HW * KC;

    // ================= phase 1: z -> zbuf, r*h -> rhpad ====================
    {
      f16x8 afz[18], afr[18];
      #pragma unroll
      for (int kt = 0; kt < 18; ++kt) {
        afz[kt] = *reinterpret_cast<const f16x8*>(uf + (size_t)(fz0 + kt) * 512);
        afr[kt] = *reinterpret_cast<const f16x8*>(uf + (size_t)(fz0 + 72 + kt) * 512);
      }
      for (int i = 0; i < ntn; ++i) {
        const int nt = ntb + i;
        const int p = nt * 16 + l16;
        const bool act = p < HW;
        const int pc = act ? p : (HW - 1);
        const int py = pc / 14, px_ = pc - py * 14;
        const int base0 = py * 16 + px_;
        const int tb = base0 * 128;
        const int rb0 = tb +       (chlo ^ ((px_ & 7) << 4));
        const int rb1 = tb + 128 + (chlo ^ (((px_ + 1) & 7) << 4));
        const int rb2 = tb + 256 + (chlo ^ (((px_ + 2) & 7) << 4));
        const int rb3 = tb +       (chhi ^ ((px_ & 7) << 4));
        const int rb4 = tb + 128 + (chhi ^ (((px_ + 1) & 7) << 4));
        const int rb5 = tb + 256 + (chhi ^ (((px_ + 2) & 7) << 4));
        const float4 wt4 = *reinterpret_cast<const float4*>(wtc + (size_t)pc * KC + ch0);
        f32x4 az = {0.f, 0.f, 0.f, 0.f};
        f32x4 ar = {0.f, 0.f, 0.f, 0.f};
        #pragma unroll
        for (int kt = 0; kt < 18; ++kt) {
          const int tap = kt >> 1, dy = tap / 3, dx = tap - dy * 3;
          const int base = (kt & 1) ? (dx == 0 ? rb3 : dx == 1 ? rb4 : rb5)
                                    : (dx == 0 ? rb0 : dx == 1 ? rb1 : rb2);
          const f16x8 bf = *reinterpret_cast<const f16x8*>(hpadB + base + dy * 2048);
          az = __builtin_amdgcn_mfma_f32_16x16x32_f16(afz[kt], bf, az, 0, 0, 0);
          ar = __builtin_amdgcn_mfma_f32_16x16x32_f16(afr[kt], bf, ar, 0, 0, 0);
        }
        if (act) {
          const float wta[4] = {wt4.x, wt4.y, wt4.z, wt4.w};
          const float4 hv = *reinterpret_cast<const float4*>(&h32[pc * 68 + ch0]);
          const float hva[4] = {hv.x, hv.y, hv.z, hv.w};
          f16x4 zw, rhw;
          #pragma unroll
          for (int jj = 0; jj < 4; ++jj) {
            float z = sigf(az[jj] + wta[jj]);
            float r = sigf(ar[jj] + wta[jj]);
            zw[jj] = (_Float16)z;
            rhw[jj] = (_Float16)(r * hva[jj]);
          }
          *reinterpret_cast<f16x4*>(reinterpret_cast<char*>(zbuf) +
              p * 128 + ((ch0 * 2) ^ ((p & 7) << 4))) = zw;
          const int ppw = base0 + 17;
          *reinterpret_cast<f16x4*>(reinterpret_cast<char*>(rhpad) +
              ppw * 128 + ((ch0 * 2) ^ ((ppw & 7) << 4))) = rhw;
        }
      }
    }
    __syncthreads();

    // ================= phase 2: hh = tanh(wt + conv(rh,Uh)); update h ======
    {
      _Float16* ad = adest + (size_t)(b * T_STEPS + tw) * HW * KC;
      f16x8 afh[18];
      #pragma unroll
      for (int kt = 0; kt < 18; ++kt)
        afh[kt] = *reinterpret_cast<const f16x8*>(uf + (size_t)(144 + fz0 + kt) * 512);
      for (int i = 0; i < ntn; ++i) {
        const int nt = ntb + i;
        const int p = nt * 16 + l16;
        const bool act = p < HW;
        const int pc = act ? p : (HW - 1);
        const int py = pc / 14, px_ = pc - py * 14;
        const int base0 = py * 16 + px_;
        const int tb = base0 * 128;
        const int rb0 = tb +       (chlo ^ ((px_ & 7) << 4));
        const int rb1 = tb + 128 + (chlo ^ (((px_ + 1) & 7) << 4));
        const int rb2 = tb + 256 + (chlo ^ (((px_ + 2) & 7) << 4));
        const int rb3 = tb +       (chhi ^ ((px_ & 7) << 4));
        const int rb4 = tb + 128 + (chhi ^ (((px_ + 1) & 7) << 4));
        const int rb5 = tb + 256 + (chhi ^ (((px_ + 2) & 7) << 4));
        const float4 wt4 = *reinterpret_cast<const float4*>(wtc + (size_t)pc * KC + ch0);
        f32x4 ah = {0.f, 0.f, 0.f, 0.f};
        #pragma unroll
        for (int kt = 0; kt < 18; ++kt) {
          const int tap = kt >> 1, dy = tap / 3, dx = tap - dy * 3;
          const int base = (kt & 1) ? (dx == 0 ? rb3 : dx == 1 ? rb4 : rb5)
                                    : (dx == 0 ? rb0 : dx == 1 ? rb1 : rb2);
          const f16x8 bf = *reinterpret_cast<const f16x8*>(rhpadB + base + dy * 2048);
          ah = __builtin_amdgcn_mfma_f32_16x16x32_f16(afh[kt], bf, ah, 0, 0, 0);
        }
        if (act) {
          const float wta[4] = {wt4.x, wt4.y, wt4.z, wt4.w};
          const f16x4 zv = *reinterpret_cast<const f16x4*>(
              reinterpret_cast<const char*>(zbuf) + p * 128 + ((ch0 * 2) ^ ((p & 7) << 4)));
          const float4 hv = *reinterpret_cast<const float4*>(&h32[pc * 68 + ch0]);
          const float hva[4] = {hv.x, hv.y, hv.z, hv.w};
          f16x4 hw;
          float hna[4];
          #pragma unroll
          for (int jj = 0; jj < 4; ++jj) {
            float hh = tanhfast(ah[jj] + wta[jj]);
            float z = (float)zv[jj];
            float hn = hh + z * (hva[jj] - hh);   // (1-z)*hh + z*h
            hna[jj] = hn;
            hw[jj] = (_Float16)hn;
          }
          float4 hn4 = {hna[0], hna[1], hna[2], hna[3]};
          *reinterpret_cast<float4*>(&h32[pc * 68 + ch0]) = hn4;
          const int ppw = base0 + 17;
          *reinterpret_cast<f16x4*>(reinterpret_cast<char*>(hpad) +
              ppw * 128 + ((ch0 * 2) ^ ((ppw & 7) << 4))) = hw;
          *reinterpret_cast<f16x4*>(ad + (size_t)pc * KC + ch0) = hw;
        }
      }
    }
    __syncthreads();
  }
}

// ---------------------------------------------------------------------------
// softmax over K=64 per pixel-row; logits = a_f + a_b (f16, [n][p][k]),
// output f16 [n][p][k] (assign in [0,1]; f16 quantization ~1e-5 abs).
// ---------------------------------------------------------------------------
__global__ __launch_bounds__(256)
void softmax_kernel(const _Float16* __restrict__ af, const _Float16* __restrict__ ab,
                    _Float16* __restrict__ out) {
  size_t idx = (size_t)blockIdx.x * 256 + threadIdx.x;   // 0..50175
  const _Float16* cf = af + idx * KC;
  const _Float16* cb = ab + idx * KC;
  _Float16* co = out + idx * KC;
  float v[KC];
  float mx = -3.4e38f;
  #pragma unroll
  for (int g = 0; g < 8; ++g) {
    f16x8 a = *reinterpret_cast<const f16x8*>(cf + g * 8);
    f16x8 bq = *reinterpret_cast<const f16x8*>(cb + g * 8);
    #pragma unroll
    for (int j = 0; j < 8; ++j) {
      float s = (float)a[j] + (float)bq[j];
      v[g * 8 + j] = s;
      mx = fmaxf(mx, s);
    }
  }
  float ssum = 0.0f;
  #pragma unroll
  for (int k = 0; k < KC; ++k) { v[k] = __expf(v[k] - mx); ssum += v[k]; }
  float inv = __builtin_amdgcn_rcpf(ssum);
  #pragma unroll
  for (int g = 0; g < 8; ++g) {
    f16x8 o;
    #pragma unroll
    for (int j = 0; j < 8; ++j) o[j] = (_Float16)(v[g * 8 + j] * inv);
    *reinterpret_cast<f16x8*>(co + g * 8) = o;
  }
}

// ---------------------------------------------------------------------------
// S[b][k] = sum over (t,p) of assign (f16 [n][p][k]). grid (8 seg, 8 b).
// ---------------------------------------------------------------------------
__global__ __launch_bounds__(256)
void sreduce_kernel(const _Float16* __restrict__ a, float* __restrict__ S) {
  __shared__ float red[4][64];
  const int seg = blockIdx.x, b = blockIdx.y, tid = threadIdx.x;
  const int k = tid & 63, rg = tid >> 6;
  const _Float16* base = a + (size_t)b * T_STEPS * HW * KC;
  float sum = 0.0f;
  for (int rr = seg * 784 + rg; rr < (seg + 1) * 784; rr += 4)
    sum += (float)base[(size_t)rr * KC + k];
  red[rg][k] = sum;
  __syncthreads();
  if (tid < 64) {
    float s = red[0][k] + red[1][k] + red[2][k] + red[3][k];
    atomicAdd(&S[b * KC + k], s);
  }
}

// ---------------------------------------------------------------------------
// VLAD GEMM partials; assign f16 [n][p][k], xrh f16 [n*196+p][512].
// grid (8 d, 8 tc, 8 b) = 512 blocks (2x TLP vs round 12), tt loop = 4.
// ---------------------------------------------------------------------------
__global__ __launch_bounds__(256)
void vlad_gemm_kernel(const _Float16* __restrict__ a, const _Float16* __restrict__ xrh,
                      float* __restrict__ Gpart) {
  __shared__ float sA[16][68];
  __shared__ float sX[16][68];
  const int tid = threadIdx.x;
  const int tx = tid & 15, ty = tid >> 4;
  const int d0 = blockIdx.x * 64;
  const int tc = blockIdx.y;
  const int b  = blockIdx.z;
  const int kk = tid & 63, pj = tid >> 6;
  float acc[4][4] = {};

  for (int tt = 0; tt < 4; ++tt) {
    int n = b * T_STEPS + tc * 4 + tt;
    const _Float16* an = a + (size_t)n * HW * KC;
    const _Float16* xn = xrh + (size_t)n * HW * DD;
    for (int p0 = 0; p0 < HW; p0 += 16) {
      __syncthreads();
      #pragma unroll
      for (int j = 0; j < 4; ++j) {
        int pl = pj * 4 + j;
        int p = p0 + pl;
        sA[pl][kk] = (p < HW) ? (float)an[(size_t)p * KC + kk] : 0.0f;
        sX[pl][kk] = (p < HW) ? (float)xn[(size_t)p * DD + d0 + kk] : 0.0f;
      }
      __syncthreads();
      #pragma unroll
      for (int pp = 0; pp < 16; ++pp) {
        float4 av = *reinterpret_cast<const float4*>(&sA[pp][ty * 4]);
        float4 xv = *reinterpret_cast<const float4*>(&sX[pp][tx * 4]);
        float aa[4] = {av.x, av.y, av.z, av.w};
        float xx[4] = {xv.x, xv.y, xv.z, xv.w};
        #pragma unroll
        for (int i = 0; i < 4; ++i)
          #pragma unroll
          for (int j = 0; j < 4; ++j)
            acc[i][j] += aa[i] * xx[j];
      }
    }
  }
  float* gp = Gpart + ((size_t)(tc * NB + b) * KC) * DD;
  #pragma unroll
  for (int i = 0; i < 4; ++i)
    #pragma unroll
    for (int j = 0; j < 4; ++j)
      gp[(ty * 4 + i) * DD + d0 + tx * 4 + j] = acc[i][j];
}

__global__ __launch_bounds__(256)
void finalize1_kernel(const float* __restrict__ Gpart, const float* __restrict__ S,
                      const float* __restrict__ centers, float* __restrict__ out,
                      float* __restrict__ bsum) {
  __shared__ float red[256];
  const int k = blockIdx.x, b = blockIdx.y, tid = threadIdx.x;
  const float sv = S[b * KC + k];
  float vals[2];
  float ss = 0.0f;
  #pragma unroll
  for (int r = 0; r < 2; ++r) {
    int d = tid + r * 256;
    float g = 0.0f;
    #pragma unroll
    for (int tc = 0; tc < 8; ++tc)
      g += Gpart[((size_t)(tc * NB + b) * KC + k) * DD + d];
    float v = g - sv * centers[k * DD + d];
    vals[r] = v; ss += v * v;
  }
  red[tid] = ss; __syncthreads();
  for (int st = 128; st > 0; st >>= 1) {
    if (tid < st) red[tid] += red[tid + st];
    __syncthreads();
  }
  float tot = red[0];
  float inv = 1.0f / fmaxf(sqrtf(tot), 1e-12f);
  #pragma unroll
  for (int r = 0; r < 2; ++r) {
    int d = tid + r * 256;
    out[(size_t)b * KC * DD + k * DD + d] = vals[r] * inv;
  }
  if (tid == 0) atomicAdd(&bsum[b], tot * inv * inv);
}

__global__ __launch_bounds__(256)
void finalize2_kernel(float* __restrict__ out, const float* __restrict__ bsum) {
  int idx = blockIdx.x * 256 + threadIdx.x;
  int b = idx >> 15;
  out[idx] = out[idx] / fmaxf(sqrtf(bsum[b]), 1e-12f);
}

// ---------------------------------------------------------------------------
extern "C" void kernel_launch(void* const* d_in, const int* in_sizes, int n_in,
                              void* d_out, int out_size, void* d_ws, size_t ws_size,
                              hipStream_t stream) {
  const float* x       = (const float*)d_in[0];
  const float* redu_w  = (const float*)d_in[1];
  const float* redu_b  = (const float*)d_in[2];
  const float* share_w = (const float*)d_in[3];
  const float* share_b = (const float*)d_in[4];
  const float* Uz      = (const float*)d_in[5];
  const float* Ur      = (const float*)d_in[6];
  const float* Uh      = (const float*)d_in[7];
  const float* centers = (const float*)d_in[8];
  float* out = (float*)d_out;

  // workspace layout (unchanged footprint vs rounds 4-12, ~172 MB):
  float* wxbc = (float*)d_ws;                                // [col][64] f32 (12.85MB)
  _Float16* assignh = (_Float16*)wxbc;                       // f16 overlay (wxbc dead after GRU)
  _Float16* xh = (_Float16*)(wxbc + (size_t)NCOL * KC);      // [col][1024] f16 (102.8MB)
  _Float16* a_f = xh;                                        // overlay (xh dead after gemmA)
  _Float16* a_b = a_f + (size_t)NFR * HW * KC;
  float* Gpart = (float*)(a_b + (size_t)NFR * HW * KC);      // 8*NB*KC*DD f32 (8.4MB), dead-xh region
  _Float16* xrh = xh + (size_t)NCOL * CIN;                   // [col][512] f16 (51.4MB)
  float* S = (float*)(xrh + (size_t)NCOL * DD);              // 512
  float* bsum = S + 512;                                     // 8
  _Float16* ufmt = (_Float16*)(bsum + 8);                    // 216*512 f16
  _Float16* wh = ufmt + 216 * 512;
  _Float16* swh = wh + (size_t)DD * CIN;

  hipMemsetAsync(bsum, 0, NB * sizeof(float), stream);
  hipMemsetAsync(S, 0, 512 * sizeof(float), stream);

  cvt_f16<<<dim3(512), 256, 0, stream>>>(redu_w, wh, DD * CIN);
  cvt_f16<<<dim3(32), 256, 0, stream>>>(share_w, swh, KC * DD);
  format_u<<<dim3(216), 64, 0, stream>>>(Uz, Ur, Uh, ufmt);
  transpose_x<<<dim3(16, 256), 256, 0, stream>>>(x, xh);

  // stage A: xrh[col][512] f16 = wh[512x1024] * xh^T
  gemm16<128, 4, true><<<dim3(392 * 4), 256, 0, stream>>>(
      wh, xh, redu_b, nullptr, xrh, DD, CIN);
  // stage B: wxbc[col][64] f32 = swh[64x512] * xrh^T
  gemm16<64, 1, false><<<dim3(392), 256, 0, stream>>>(
      swh, xrh, share_b, wxbc, nullptr, KC, DD);

  // GRU: round-10 proven kernel (443 us)
  gru_mfma8<<<dim3(16), 512, 0, stream>>>(wxbc, ufmt, a_f, a_b);

  softmax_kernel<<<dim3(196), 256, 0, stream>>>(a_f, a_b, assignh);
  sreduce_kernel<<<dim3(8, 8), 256, 0, stream>>>(assignh, S);
  vlad_gemm_kernel<<<dim3(8, 8, 8), 256, 0, stream>>>(assignh, xrh, Gpart);
  finalize1_kernel<<<dim3(64, 8), 256, 0, stream>>>(Gpart, S, centers, out, bsum);
  finalize2_kernel<<<dim3(1024), 256, 0, stream>>>(out, bsum);
}